// Round 2
// baseline (815.163 us; speedup 1.0000x reference)
//
#include <hip/hip_runtime.h>

// Problem constants
#define H        16
#define HD       128
#define IN_DIM   1024
#define QKV_DIM  6144   // 3*H*HD
#define OUT_DIM  1024
#define B_TOTAL  32768  // 64*512
#define CHUNK    8192
#define NCHUNK   4

typedef unsigned short u16;
typedef __attribute__((ext_vector_type(8))) __bf16 bf16x8;
typedef __attribute__((ext_vector_type(4))) float  f32x4;

__device__ __forceinline__ u16 f2bf(float f) {
  unsigned u = __float_as_uint(f);
  u += 0x7fff + ((u >> 16) & 1);   // RNE
  return (u16)(u >> 16);
}
__device__ __forceinline__ float bf2f(u16 s) {
  return __uint_as_float(((unsigned)s) << 16);
}

#define GLDS16(gp, lp) __builtin_amdgcn_global_load_lds( \
    (__attribute__((address_space(1))) void*)(gp), \
    (__attribute__((address_space(3))) void*)(lp), 16, 0, 0)

// ---------------- fp32 -> bf16 convert (vectorized) ----------------
__global__ void cvt_x(const float* __restrict__ src, u16* __restrict__ dst, int n8) {
  int stride = gridDim.x * blockDim.x;
  for (int i = blockIdx.x * blockDim.x + threadIdx.x; i < n8; i += stride) {
    const float4* s = (const float4*)(src + (size_t)i * 8);
    float4 f0 = s[0], f1 = s[1];
    ushort4 o0, o1;
    o0.x = f2bf(f0.x); o0.y = f2bf(f0.y); o0.z = f2bf(f0.z); o0.w = f2bf(f0.w);
    o1.x = f2bf(f1.x); o1.y = f2bf(f1.y); o1.z = f2bf(f1.z); o1.w = f2bf(f1.w);
    *(ushort4*)(dst + (size_t)i * 8)     = o0;
    *(ushort4*)(dst + (size_t)i * 8 + 4) = o1;
  }
}

// ------------- transpose + convert: src[R][C] f32 -> dst[C][R] bf16 -------------
// R, C multiples of 32. block=256 (32x8), grid=(C/32, R/32)
__global__ void transpose_cvt(const float* __restrict__ src, u16* __restrict__ dst,
                              int R, int C) {
  __shared__ float tile[32][33];
  int tx = threadIdx.x & 31, ty = threadIdx.x >> 5;  // ty 0..7
  int c0 = blockIdx.x * 32, r0 = blockIdx.y * 32;
  #pragma unroll
  for (int i = 0; i < 32; i += 8)
    tile[ty + i][tx] = src[(size_t)(r0 + ty + i) * C + c0 + tx];
  __syncthreads();
  #pragma unroll
  for (int i = 0; i < 32; i += 8)
    dst[(size_t)(c0 + ty + i) * R + r0 + tx] = f2bf(tile[tx][ty + i]);
}

// ---------------- GEMM1: qkv[M][6144] = xb[M][1024] @ wpreT[6144][1024]^T + b ----------------
// m97 structure: 128x128 tile, BK=32, 4 waves, global_load_lds width 16.
__global__ void gemm1(const u16* __restrict__ A, const u16* __restrict__ BT,
                      const float* __restrict__ bias, u16* __restrict__ Cq) {
  __shared__ u16 As[128 * 32];
  __shared__ u16 Bs[128 * 32];
  int tid = threadIdx.x;
  int lane = tid & 63, wave = tid >> 6;
  int wm = wave >> 1, wn = wave & 1;
  int m0 = blockIdx.y * 128, n0 = blockIdx.x * 128;

  f32x4 zero = {0.f, 0.f, 0.f, 0.f};
  f32x4 acc[4][4];
  #pragma unroll
  for (int m = 0; m < 4; ++m)
    #pragma unroll
    for (int n = 0; n < 4; ++n) acc[m][n] = zero;

  for (int k0 = 0; k0 < IN_DIM; k0 += 32) {
    #pragma unroll
    for (int i = 0; i < 2; ++i) {
      int idx = i * 256 + tid;           // 0..511, = i*256 + wave*64 + lane
      int row = idx >> 2, kc = (idx & 3) * 8;
      GLDS16(A  + (size_t)(m0 + row) * IN_DIM + k0 + kc, As + (size_t)(i * 256 + wave * 64) * 8);
      GLDS16(BT + (size_t)(n0 + row) * IN_DIM + k0 + kc, Bs + (size_t)(i * 256 + wave * 64) * 8);
    }
    __syncthreads();
    bf16x8 af[4], bv[4];
    #pragma unroll
    for (int m = 0; m < 4; ++m)
      af[m] = *(const bf16x8*)&As[(wm * 64 + m * 16 + (lane & 15)) * 32 + (lane >> 4) * 8];
    #pragma unroll
    for (int n = 0; n < 4; ++n)
      bv[n] = *(const bf16x8*)&Bs[(wn * 64 + n * 16 + (lane & 15)) * 32 + (lane >> 4) * 8];
    #pragma unroll
    for (int m = 0; m < 4; ++m)
      #pragma unroll
      for (int n = 0; n < 4; ++n)
        acc[m][n] = __builtin_amdgcn_mfma_f32_16x16x32_bf16(af[m], bv[n], acc[m][n], 0, 0, 0);
    __syncthreads();
  }

  int rbase = m0 + wm * 64 + (lane >> 4) * 4;
  int cbase = n0 + wn * 64 + (lane & 15);
  #pragma unroll
  for (int m = 0; m < 4; ++m)
    #pragma unroll
    for (int n = 0; n < 4; ++n) {
      int ccol = cbase + n * 16;
      float bb = bias[ccol];
      #pragma unroll
      for (int j = 0; j < 4; ++j) {
        int rr = rbase + m * 16 + j;
        Cq[(size_t)rr * QKV_DIM + ccol] = f2bf(acc[m][n][j] + bb);
      }
    }
}

// ---------------- attention: per row, scores -> softmax -> column-sum w -> w @ v ----------------
// 1 wave per row, 4 rows per block.
__global__ void attn(const u16* __restrict__ qkv, u16* __restrict__ attsum) {
  int wave = threadIdx.x >> 6, lane = threadIdx.x & 63;
  int b = blockIdx.x * 4 + wave;
  const u16* q = qkv + (size_t)b * QKV_DIM;
  const u16* k = q + H * HD;
  const u16* v = q + 2 * H * HD;

  int hr = lane & 15, kc = (lane >> 4) * 8;
  f32x4 sc = {0.f, 0.f, 0.f, 0.f};
  #pragma unroll
  for (int s = 0; s < 4; ++s) {
    bf16x8 aq = *(const bf16x8*)&q[hr * HD + s * 32 + kc];
    bf16x8 ak = *(const bf16x8*)&k[hr * HD + s * 32 + kc];
    sc = __builtin_amdgcn_mfma_f32_16x16x32_bf16(aq, ak, sc, 0, 0, 0);
  }
  // sc[j] = score[row=(lane>>4)*4+j][col=lane&15]
  const float scale = 0.08838834764831845f;  // 1/sqrt(128)
  float w = 0.f;
  #pragma unroll
  for (int j = 0; j < 4; ++j) {
    float xv = sc[j] * scale;
    float mx = xv;
    #pragma unroll
    for (int d = 1; d < 16; d <<= 1) mx = fmaxf(mx, __shfl_xor(mx, d));
    float e = __expf(xv - mx);
    float s = e;
    #pragma unroll
    for (int d = 1; d < 16; d <<= 1) s += __shfl_xor(s, d);
    w += e / s;   // p[row][col]
  }
  // sum the 4 row-groups -> w[g = lane&15] in every lane
  w += __shfl_xor(w, 16);
  w += __shfl_xor(w, 32);

  float a0 = 0.f, a1 = 0.f;
  #pragma unroll
  for (int g = 0; g < 16; ++g) {
    float wg = __shfl(w, g);
    a0 += wg * bf2f(v[g * HD + lane]);
    a1 += wg * bf2f(v[g * HD + 64 + lane]);
  }
  attsum[(size_t)b * HD + lane]      = f2bf(a0);
  attsum[(size_t)b * HD + 64 + lane] = f2bf(a1);
}

// ---------------- GEMM2: out[M][1024] = attsum[M][128] @ wprojT[1024][128]^T + 16*b ----------------
__global__ void gemm2(const u16* __restrict__ A, const u16* __restrict__ BT,
                      const float* __restrict__ bias, float* __restrict__ out) {
  __shared__ u16 As[128 * 128];
  __shared__ u16 Bs[128 * 128];
  int tid = threadIdx.x, lane = tid & 63, wave = tid >> 6;
  int wm = wave >> 1, wn = wave & 1;
  int m0 = blockIdx.y * 128, n0 = blockIdx.x * 128;

  #pragma unroll
  for (int i = 0; i < 8; ++i) {
    int idx = i * 256 + tid;            // 0..2047
    int row = idx >> 4, kc = (idx & 15) * 8;
    GLDS16(A  + (size_t)(m0 + row) * HD + kc, As + (size_t)(i * 256 + wave * 64) * 8);
    GLDS16(BT + (size_t)(n0 + row) * HD + kc, Bs + (size_t)(i * 256 + wave * 64) * 8);
  }
  __syncthreads();

  f32x4 zero = {0.f, 0.f, 0.f, 0.f};
  f32x4 acc[4][4];
  #pragma unroll
  for (int m = 0; m < 4; ++m)
    #pragma unroll
    for (int n = 0; n < 4; ++n) acc[m][n] = zero;

  #pragma unroll
  for (int s = 0; s < 4; ++s) {
    bf16x8 af[4], bv[4];
    #pragma unroll
    for (int m = 0; m < 4; ++m)
      af[m] = *(const bf16x8*)&As[(wm * 64 + m * 16 + (lane & 15)) * HD + s * 32 + (lane >> 4) * 8];
    #pragma unroll
    for (int n = 0; n < 4; ++n)
      bv[n] = *(const bf16x8*)&Bs[(wn * 64 + n * 16 + (lane & 15)) * HD + s * 32 + (lane >> 4) * 8];
    #pragma unroll
    for (int m = 0; m < 4; ++m)
      #pragma unroll
      for (int n = 0; n < 4; ++n)
        acc[m][n] = __builtin_amdgcn_mfma_f32_16x16x32_bf16(af[m], bv[n], acc[m][n], 0, 0, 0);
  }

  int rbase = m0 + wm * 64 + (lane >> 4) * 4;
  int cbase = n0 + wn * 64 + (lane & 15);
  #pragma unroll
  for (int m = 0; m < 4; ++m)
    #pragma unroll
    for (int n = 0; n < 4; ++n) {
      int ccol = cbase + n * 16;
      float bb = 16.f * bias[ccol];
      #pragma unroll
      for (int j = 0; j < 4; ++j) {
        int rr = rbase + m * 16 + j;
        out[(size_t)rr * OUT_DIM + ccol] = acc[m][n][j] + bb;
      }
    }
}

extern "C" void kernel_launch(void* const* d_in, const int* in_sizes, int n_in,
                              void* d_out, int out_size, void* d_ws, size_t ws_size,
                              hipStream_t stream) {
  const float* x      = (const float*)d_in[0];
  const float* W_pre  = (const float*)d_in[1];
  const float* b_pre  = (const float*)d_in[2];
  const float* W_proj = (const float*)d_in[3];
  const float* b_proj = (const float*)d_in[4];
  float* out = (float*)d_out;

  // workspace layout (bf16 = u16 elements), total ~132.4 MB
  u16* wpreT  = (u16*)d_ws;                               // [6144][1024]
  u16* wprojT = wpreT  + (size_t)QKV_DIM * IN_DIM;        // [1024][128]
  u16* xb     = wprojT + (size_t)OUT_DIM * HD;            // [CHUNK][1024]
  u16* qkvb   = xb     + (size_t)CHUNK * IN_DIM;          // [CHUNK][6144]
  u16* attb   = qkvb   + (size_t)CHUNK * QKV_DIM;         // [CHUNK][128]

  transpose_cvt<<<dim3(QKV_DIM / 32, IN_DIM / 32), 256, 0, stream>>>(W_pre, wpreT, IN_DIM, QKV_DIM);
  transpose_cvt<<<dim3(OUT_DIM / 32, HD / 32), 256, 0, stream>>>(W_proj, wprojT, HD, OUT_DIM);

  for (int c = 0; c < NCHUNK; ++c) {
    const float* xc = x + (size_t)c * CHUNK * IN_DIM;
    cvt_x<<<1024, 256, 0, stream>>>(xc, xb, CHUNK * IN_DIM / 8);
    gemm1<<<dim3(QKV_DIM / 128, CHUNK / 128), 256, 0, stream>>>(xb, wpreT, b_pre, qkvb);
    attn<<<CHUNK / 4, 256, 0, stream>>>(qkvb, attb);
    gemm2<<<dim3(OUT_DIM / 128, CHUNK / 128), 256, 0, stream>>>(attb, wprojT, b_proj,
                                                                out + (size_t)c * CHUNK * OUT_DIM);
  }
}